// Round 7
// baseline (155.162 us; speedup 1.0000x reference)
//
#include <hip/hip_runtime.h>

// ComplexMixture: B=32, S=8192, D=64, fp32 in/out.
// out_real = (R^T R + I^T I)/S   [B,64,64]  (symmetric)
// out_imag = (R^T I - (R^T I)^T)/S          (antisymmetric)
// R9 = R8 resubmit (previous round was an infra failure, not a kernel fail).
// Concurrency x pipelining: 4 resident blocks/CU (32 KB dbuf LDS, grid
// 1024 = CHUNKS 32, launch_bounds(256,4)) AND depth-2 register prefetch
// (64 staging VGPRs, vmcnt never drains in-loop). Quadrant split
// (2 accs/wave in AGPRs), mat-split staging, atomic-output epilogue.

#define BATCH  32
#define SEQ    8192
#define DD     64
#define CHUNKS 32
#define SCHUNK (SEQ / CHUNKS)   // 256 rows per block
#define TR     64               // rows per tile
#define NIT    (SCHUNK / TR)    // 4 tiles

typedef __bf16 bf16x8 __attribute__((ext_vector_type(8)));
typedef float  f32x16 __attribute__((ext_vector_type(16)));
typedef float  f32x4  __attribute__((ext_vector_type(4)));

__device__ __forceinline__ unsigned bf16pk(float a, float b) {
  unsigned ua = __builtin_bit_cast(unsigned, a);
  unsigned ub = __builtin_bit_cast(unsigned, b);
  ua = (ua + 0x7fffu + ((ua >> 16) & 1u)) >> 16;   // RNE to bf16
  ub = (ub + 0x7fffu + ((ub >> 16) & 1u)) >> 16;
  return (ua & 0xffffu) | (ub << 16);
}

// Column permutation (uint4 units within a 64-entry row); bank-conflict-free
// for both 16-lane ds_write groups and 32-lane ds_read_b128 fragment reads
// (0 conflicts measured R4-R7 with identical geometry).
__device__ __forceinline__ int permd(int d) {
  return d ^ ((d >> 3) & 1) ^ (((d >> 4) & 1) << 1);
}

__device__ __forceinline__ void atomAdd(float* p, float v) {
  __hip_atomic_fetch_add(p, v, __ATOMIC_RELAXED, __HIP_MEMORY_SCOPE_AGENT);
}

// lds[buf][mat][kg][entry]: double-buffered 64-row tile, mat 0=R 1=I.
// Row kg holds s-rows kg*8..+8 as k-contiguous bf16x8; entry = permd(d).
// 2*2*8*64*16B = 32 KB -> 4 blocks/CU.
__global__ __launch_bounds__(256, 4) void gram_fused(
    const float* __restrict__ R, const float* __restrict__ I,
    float* __restrict__ out)
{
  __shared__ uint4 lds[2][2][8][64];
  const int tid  = threadIdx.x;
  const int wave = tid >> 6;
  const int lane = tid & 63;
  const int l31  = lane & 31;
  const int lhi  = lane >> 5;
  const int mat  = tid >> 7;            // waves 0-1 stage R, waves 2-3 stage I
  const int g    = (tid >> 4) & 7;      // row-group (rows g*8..+8 of tile)
  const int q    = tid & 15;            // float4 column index
  const int b = blockIdx.x & 31;
  const int c = blockIdx.x >> 5;
  const float* Mb = (mat ? I : R) + (size_t)b * (SEQ * DD);
  const int m0 = (wave >> 1) * 32;      // output quadrant of this wave
  const int n0 = (wave & 1) * 32;
  const int pa = permd(m0 + l31);
  const int pb = permd(n0 + l31);
  int pw[4];
  #pragma unroll
  for (int cc = 0; cc < 4; ++cc) pw[cc] = permd(q * 4 + cc);

  f32x16 accR = {};   // rr + ii quadrant (m0,n0)
  f32x16 accI = {};   // ri quadrant (m0,n0)

  f32x4 v[2][8];      // 64 staging regs: 2 bursts in flight
  const size_t rbase = (size_t)(c * SCHUNK + g * 8) * DD;

  // issue the 8-load burst for tile t_ into regset rs_
#define LOADT(t_, rs_) do { \
    const f32x4* p_ = (const f32x4*)(Mb + rbase + (size_t)(t_) * TR * DD) + q; \
    _Pragma("unroll") \
    for (int j = 0; j < 8; ++j) v[rs_][j] = p_[j * 16]; \
    asm volatile("" ::: "memory"); \
  } while (0)

  // convert + write regset rs_ into buffer buf_ (counted vmcnt lands here:
  // only the older burst is waited, the newer one stays outstanding)
#define PACKW(buf_, rs_) do { \
    _Pragma("unroll") \
    for (int cc = 0; cc < 4; ++cc) { \
      uint4 u_; \
      u_.x = bf16pk(v[rs_][0][cc], v[rs_][1][cc]); \
      u_.y = bf16pk(v[rs_][2][cc], v[rs_][3][cc]); \
      u_.z = bf16pk(v[rs_][4][cc], v[rs_][5][cc]); \
      u_.w = bf16pk(v[rs_][6][cc], v[rs_][7][cc]); \
      lds[buf_][mat][g][pw[cc]] = u_; \
    } \
  } while (0)

  // barrier with no vmcnt drain; sched_barrier both sides (rule #18)
#define TILEBAR() do { \
    __builtin_amdgcn_sched_barrier(0); \
    asm volatile("s_waitcnt lgkmcnt(0)" ::: "memory"); \
    __builtin_amdgcn_s_barrier(); \
    __builtin_amdgcn_sched_barrier(0); \
  } while (0)

  // prologue: 2 bursts in flight, pack tile 0
  LOADT(0, 0);
  LOADT(1, 1);
  PACKW(0, 0);
  TILEBAR();

  #pragma unroll
  for (int t = 0; t < NIT; ++t) {
    if (t + 2 < NIT) LOADT(t + 2, (t + 2) & 1);   // keep 2 bursts outstanding
    const int buf = t & 1;
    #pragma unroll
    for (int ks = 0; ks < TR / 16; ++ks) {
      const int kg = ks * 2 + lhi;
      bf16x8 aR = __builtin_bit_cast(bf16x8, lds[buf][0][kg][pa]);
      bf16x8 bR = __builtin_bit_cast(bf16x8, lds[buf][0][kg][pb]);
      bf16x8 aI = __builtin_bit_cast(bf16x8, lds[buf][1][kg][pa]);
      bf16x8 bI = __builtin_bit_cast(bf16x8, lds[buf][1][kg][pb]);
      accR = __builtin_amdgcn_mfma_f32_32x32x16_bf16(aR, bR, accR, 0, 0, 0);
      accR = __builtin_amdgcn_mfma_f32_32x32x16_bf16(aI, bI, accR, 0, 0, 0);
      accI = __builtin_amdgcn_mfma_f32_32x32x16_bf16(aR, bI, accI, 0, 0, 0);
    }
    if (t + 1 < NIT) {
      PACKW(buf ^ 1, (t + 1) & 1);      // other buffer; readers sync'd by bar
      TILEBAR();                        // single barrier per tile
    }
  }
#undef LOADT
#undef PACKW
#undef TILEBAR

  // ---- epilogue: atomic-accumulate scaled partials into out ----
  const float inv = 1.0f / (float)SEQ;
  float* outR = out + (size_t)b * 4096;
  float* outM = out + 131072 + (size_t)b * 4096;
  const int jj = n0 + l31;

  // real: direct from regs (full 64x64 covered by the 4 quadrants)
  #pragma unroll
  for (int r = 0; r < 16; ++r) {
    const int i = m0 + (r & 3) + 8 * (r >> 2) + 4 * lhi;
    atomAdd(&outR[i * 64 + jj], accR[r] * inv);
  }

  // imag: antisymmetrize via LDS scratch (64x65 f32 = 16.6 KB), then atomics.
  __syncthreads();                      // all MFMA reads done before overwrite
  float* sc = (float*)lds;
  #pragma unroll
  for (int r = 0; r < 16; ++r) {
    const int i = m0 + (r & 3) + 8 * (r >> 2) + 4 * lhi;
    sc[i * 65 + jj] = accI[r];
  }
  __syncthreads();
  #pragma unroll
  for (int r = 0; r < 16; ++r) {
    const int i = m0 + (r & 3) + 8 * (r >> 2) + 4 * lhi;
    const float m = (sc[i * 65 + jj] - sc[jj * 65 + i]) * inv;
    atomAdd(&outM[i * 64 + jj], m);
  }
}

extern "C" void kernel_launch(void* const* d_in, const int* in_sizes, int n_in,
                              void* d_out, int out_size, void* d_ws, size_t ws_size,
                              hipStream_t stream) {
  const float* R = (const float*)d_in[0];
  const float* I = (const float*)d_in[1];
  float* out = (float*)d_out;
  (void)d_ws; (void)ws_size;

  hipMemsetAsync(d_out, 0, (size_t)out_size, stream);   // capture-safe
  gram_fused<<<BATCH * CHUNKS, 256, 0, stream>>>(R, I, out);
}